// Round 9
// baseline (3087.578 us; speedup 1.0000x reference)
//
#include <hip/hip_runtime.h>
#include <math.h>

#define TT 50
#define BB 256
#define FF 96
#define HH 512
#define G3 1536
#define RNN_IN 288
#define HSZ (BB * HH)

typedef __attribute__((ext_vector_type(8))) short bhalf8;
typedef __attribute__((ext_vector_type(4))) float floatx4;
#define MFMA16 __builtin_amdgcn_mfma_f32_16x16x32_bf16

__device__ inline ushort f2bf(float f) {
    union { float f; unsigned u; } v; v.f = f;
    unsigned r = (v.u + 0x7FFFu + ((v.u >> 16) & 1u)) >> 16;
    return (ushort)r;
}
__device__ inline float bf2f(ushort h) {
    union { unsigned u; float f; } v; v.u = ((unsigned)h) << 16; return v.f;
}
__device__ inline bhalf8 ld8(const ushort* p) { return *(const bhalf8*)p; }
__device__ inline float sigmoidf_(float x) { return 1.f / (1.f + __expf(-x)); }

__device__ inline float pe_val(int pos, int d) {
    float dv = expf(-9.210340371976184f * (float)(d & ~1) / 96.0f);
    float a = (float)pos * dv;
    return (d & 1) ? cosf(a) : sinf(a);
}

// ~512 VALU instructions of dummy FMA (4 independent chains). Keeps the SIMD
// issuing so DPM sees activity during sync waits. ~0.2us at 2.4GHz.
__device__ inline void burn512(float seed) {
    float a0 = seed, a1 = seed + 1.f, a2 = seed + 2.f, a3 = seed + 3.f;
#pragma unroll
    for (int i = 0; i < 128; i++) {
        asm volatile("v_fmac_f32 %0, %1, %2" : "+v"(a0) : "v"(a1), "v"(a2));
        asm volatile("v_fmac_f32 %0, %1, %2" : "+v"(a1) : "v"(a2), "v"(a3));
        asm volatile("v_fmac_f32 %0, %1, %2" : "+v"(a2) : "v"(a3), "v"(a0));
        asm volatile("v_fmac_f32 %0, %1, %2" : "+v"(a3) : "v"(a0), "v"(a1));
    }
    asm volatile("" :: "v"(a0), "v"(a1), "v"(a2), "v"(a3));
}

// ---------------- prep: weight cast fp32 -> bf16 ----------------
__global__ __launch_bounds__(256) void prep_weights(
    const float* Wih0, const float* Whh0, const float* Wih1, const float* Whh1, const float* Wlin,
    ushort* dWih0, ushort* dWhh0, ushort* dWih1, ushort* dWhh1, ushort* dWlin)
{
    const int n0 = G3 * RNN_IN;
    const int n1 = G3 * HH;
    const int n2 = FF * HH;
    const int total = n0 + 3 * n1 + n2;
    for (int i = blockIdx.x * 256 + threadIdx.x; i < total; i += gridDim.x * 256) {
        int j = i;
        if (j < n0) { dWih0[j] = f2bf(Wih0[j]); continue; }
        j -= n0;
        if (j < n1) { dWhh0[j] = f2bf(Whh0[j]); continue; }
        j -= n1;
        if (j < n1) { dWih1[j] = f2bf(Wih1[j]); continue; }
        j -= n1;
        if (j < n1) { dWhh1[j] = f2bf(Whh1[j]); continue; }
        j -= n1;
        dWlin[j] = f2bf(Wlin[j]);
    }
}

// ---------------- prep: pe, mask, x_en, h init, slots zero ----------------
__global__ __launch_bounds__(256) void prep_misc(
    const float* __restrict__ input, float* pe, float* maskp, ushort* x_en,
    ushort* hb, unsigned* bar)
{
    int i = blockIdx.x * 256 + threadIdx.x;
    if (i < TT * BB * RNN_IN) {
        int t = i / (BB * RNN_IN);
        int r = i % (BB * RNN_IN);
        int b = r / RNN_IN, c = r % RNN_IN;
        float v;
        if (c < FF) v = input[(t * BB + b) * FF + c];
        else if (c < 2 * FF) {
            int cc = c - FF;
            v = (t == 0) ? 0.f : input[(t * BB + b) * FF + cc] - input[((t - 1) * BB + b) * FF + cc];
        } else v = pe_val(t, c - 2 * FF);
        x_en[i] = f2bf(v);
        return;
    }
    i -= TT * BB * RNN_IN;
    if (i < BB * FF) {
        int b = i / FF, f = i % FF;
        float mean = 0.f, sq = 0.f;
        for (int t = 0; t < TT; t++) {
            float x = input[(t * BB + b) * FF + f];
            mean += x; sq += x * x;
        }
        mean /= (float)TT;
        float var = (sq - (float)TT * mean * mean) / (float)(TT - 1);
        float sd = sqrtf(fmaxf(var, 0.f));
        maskp[i] = (sd > 1e-4f) ? 1.f : 0.f;
        return;
    }
    i -= BB * FF;
    if (i < 100 * FF) { pe[i] = pe_val(i / FF, i % FF); return; }
    i -= 100 * FF;
    if (i < 4 * BB * HH) { hb[i] = 0; return; }   // h0buf[2] + h1buf[2]
    i -= 4 * BB * HH;
    if (i < 8192) { bar[i] = 0; return; }          // 128 slots x 64 uints (256B lines)
}

// ---------------- Zpe: pe_dec part of decoder gi0 (+ b_ih0 folded) ----------------
__global__ __launch_bounds__(256) void zpe_kernel(
    const float* __restrict__ pe, const float* __restrict__ Wih0,
    const float* __restrict__ bih0, float* __restrict__ Zpe)
{
    int idx = blockIdx.x * 256 + threadIdx.x;
    if (idx >= TT * G3) return;
    int t = idx / G3, n = idx % G3;
    float s = bih0[n];
    const float* per = pe + (TT + t) * FF;
    const float* wr = Wih0 + n * RNN_IN + 2 * FF;
    for (int k = 0; k < FF; k++) s += per[k] * wr[k];
    Zpe[idx] = s;
}

// ---------------- Zvel0: input[0] + vel parts of decoder step-0 gi0 ----------------
__global__ __launch_bounds__(256) void zvel_kernel(
    const float* __restrict__ input, const float* __restrict__ Wih0, float* __restrict__ Zvel)
{
    int idx = blockIdx.x * 256 + threadIdx.x;
    if (idx >= BB * G3) return;
    int m = idx / G3, n = idx % G3;
    const float* a0 = input + m * FF;                       // input[0]
    const float* aL = input + (TT - 1) * BB * FF + m * FF;  // input[-1]
    const float* wr = Wih0 + n * RNN_IN;
    float s = 0.f;
    for (int k = 0; k < FF; k++) s += a0[k] * wr[k] + (a0[k] - aL[k]) * wr[FF + k];
    Zvel[idx] = s;
}

// ---------------- big GEMM: Z0[t][b][gatecol] = bf16(x_en @ Wih0^T + b_ih0) ----------------
__global__ __launch_bounds__(256) void gemm_z0(
    const ushort* __restrict__ A, const ushort* __restrict__ W,
    const float* __restrict__ bias, ushort* __restrict__ C)
{
    int lane = threadIdx.x & 63, w = threadIdx.x >> 6;
    int row0 = blockIdx.x * 64 + w * 16;
    int c0 = blockIdx.y * 96;
    int l15 = lane & 15, q = lane >> 4;
    const ushort* ap = A + (size_t)(row0 + l15) * RNN_IN + q * 8;
    floatx4 acc[6] = {};
    const ushort* wp[6];
#pragma unroll
    for (int j = 0; j < 6; j++) wp[j] = W + (size_t)(c0 + 16 * j + l15) * RNN_IN + q * 8;
    for (int kt = 0; kt < RNN_IN / 32; kt++) {
        bhalf8 a = ld8(ap + kt * 32);
#pragma unroll
        for (int j = 0; j < 6; j++) {
            bhalf8 b = ld8(wp[j] + kt * 32);
            acc[j] = MFMA16(a, b, acc[j], 0, 0, 0);
        }
    }
#pragma unroll
    for (int j = 0; j < 6; j++) {
        int col = c0 + 16 * j + l15;
        float bb = bias[col];
#pragma unroll
        for (int i = 0; i < 4; i++) {
            int r = row0 + q * 4 + i;
            C[(size_t)r * G3 + col] = f2bf(acc[j][i] + bb);
        }
    }
}

// ---------------- enc outputs: out = outs @ Wlin^T + b_lin + input ----------------
__global__ __launch_bounds__(256) void gemm_out_enc(
    const ushort* __restrict__ A, const ushort* __restrict__ W,
    const float* __restrict__ bias, const float* __restrict__ addsrc, float* __restrict__ out)
{
    int lane = threadIdx.x & 63, w = threadIdx.x >> 6;
    int row0 = blockIdx.x * 64 + w * 16;
    int l15 = lane & 15, q = lane >> 4;
    const ushort* ap = A + (size_t)(row0 + l15) * HH + q * 8;
    floatx4 acc[6] = {};
    const ushort* wp[6];
#pragma unroll
    for (int j = 0; j < 6; j++) wp[j] = W + (size_t)(16 * j + l15) * HH + q * 8;
    for (int kt = 0; kt < HH / 32; kt++) {
        bhalf8 a = ld8(ap + kt * 32);
#pragma unroll
        for (int j = 0; j < 6; j++) {
            bhalf8 b = ld8(wp[j] + kt * 32);
            acc[j] = MFMA16(a, b, acc[j], 0, 0, 0);
        }
    }
#pragma unroll
    for (int j = 0; j < 6; j++) {
        int col = 16 * j + l15;
        float bb = bias[col];
#pragma unroll
        for (int i = 0; i < 4; i++) {
            int r = row0 + q * 4 + i;
            out[(size_t)r * FF + col] = acc[j][i] + bb + addsrc[(size_t)r * FF + col];
        }
    }
}

// ================= persistent cooperative kernel =================
// Identical to r8 (split barrier: release early / wait late) EXCEPT the wait:
// s_sleep poll replaced by a VALU-burning poll in all 4 waves (wave 0 polls
// global slots between 512-FMA burns; waves 1-3 poll an LDS flag between
// burns). Purpose: keep every active SIMD issuing so DPM holds clocks up
// during the sync windows that dominate each phase.

struct PArgs {
    const ushort* Z0;         // [TT][BB][G3]
    const ushort* Wih0b;      // [G3][288]
    const ushort* Whh0b; const ushort* Wih1b; const ushort* Whh1b;  // [G3][512]
    const ushort* Wlinb;      // [96][512]
    const float* bhh0; const float* bih1; const float* bhh1; const float* blin;
    const float* Zpe;         // [TT][G3]
    const float* Zvel;        // [BB][G3]
    const float* maskp;       // [BB][96]
    const float* input;       // input[0] for pred init
    ushort* h0buf;            // [2][BB][HH]
    ushort* h1buf;            // [2][BB][HH]
    ushort* outs;             // [TT][BB][HH]
    float* out;
    unsigned* slots;          // 128 slots x 64 uints (256B lines)
};

__global__ __launch_bounds__(256) void persistent7(PArgs P)
{
    const int tid = threadIdx.x;
    const int w = tid >> 6;
    const int lane = tid & 63;
    const int l15 = lane & 15, q = lane >> 4;
    const int rg = blockIdx.x >> 3, cg = blockIdx.x & 7;
    const int row0 = rg * 16;
    const int ct = cg * 64 + w * 16;      // wave's 16-col base
    const int bcol = ct + q * 4;          // thread's first of 4 h-cols
    const int lcol = w * 16 + q * 4;      // within block's 64-col LDS slice

    __shared__ ushort h0stage[8192];      // [kt][q][l15][8] B-frag order
    __shared__ ushort h1stage[8192];
    __shared__ float h0f[16][68];
    __shared__ float h1f[16][68];
    __shared__ float predf[16][100];
    __shared__ float maskl[16][100];
    __shared__ ushort predb[16][104];
    __shared__ unsigned dflag;

    for (int i = tid; i < 16 * 68; i += 256) { ((float*)h0f)[i] = 0.f; ((float*)h1f)[i] = 0.f; }
    for (int i = tid; i < 16 * 96; i += 256) {
        int r = i / 96, c = i % 96;
        float p0 = P.input[(row0 + r) * FF + c];
        predf[r][c] = p0;
        predb[r][c] = f2bf(p0);
        maskl[r][c] = P.maskp[(row0 + r) * FF + c];
    }
    if (tid == 0) dflag = 0;
    __syncthreads();

    unsigned phase = 0;
    unsigned* myslot = P.slots + (size_t)(rg * 8 + cg) * 64;
    const unsigned* pslot = P.slots + (size_t)(rg * 8 + (tid & 7)) * 64;

    // signal early: drain our stores, then publish phase
    auto release = [&]() {
        phase++;
        asm volatile("s_waitcnt vmcnt(0)" ::: "memory");
        __syncthreads();
        if (tid == 0)
            __hip_atomic_store(myslot, phase, __ATOMIC_RELAXED, __HIP_MEMORY_SCOPE_AGENT);
    };

    // wait late: VALU-burning poll (keeps clocks pinned)
    auto wait_ = [&]() {
        volatile unsigned* df = &dflag;
        if (w == 0) {
            const bool polls = (tid < 8) && (tid != cg);
            for (;;) {
                burn512((float)phase + (float)lane);
                int ok = 1;
                if (polls)
                    ok = (__hip_atomic_load(pslot, __ATOMIC_RELAXED, __HIP_MEMORY_SCOPE_AGENT) >= phase);
                if (__all(ok)) break;
            }
            if (tid == 0) *df = phase;
        } else {
            while (*df < phase) burn512((float)phase + (float)lane);
        }
        __syncthreads();
        asm volatile("" ::: "memory");
    };

    // cooperative stage: 16 rows x 512 cols bf16 -> LDS [kt][q][l15][8]
    auto stage = [&](const ushort* src, ushort* dst) {
        const int r = tid & 15;
        const int cb = tid >> 4;
        const unsigned long long* gp =
            (const unsigned long long*)(src + (size_t)(row0 + r) * HH + cb * 32);
        unsigned long long v[8];
#pragma unroll
        for (int j = 0; j < 8; j++)
            v[j] = __hip_atomic_load(gp + j, __ATOMIC_RELAXED, __HIP_MEMORY_SCOPE_AGENT);
#pragma unroll
        for (int qq = 0; qq < 4; qq++) {
            unsigned long long* lp = (unsigned long long*)(dst + ((cb * 4 + qq) * 16 + r) * 8);
            lp[0] = v[2 * qq];
            lp[1] = v[2 * qq + 1];
        }
    };

    // 3-gate GEMM: A=W rows (plain L2 loads), B=h from staged LDS
    auto gemm3_lds = [&](const ushort* hst, const ushort* W, floatx4 acc[3]) {
        const ushort* a0 = W + (size_t)(0 * HH + ct + l15) * HH + q * 8;
        const ushort* a1 = W + (size_t)(1 * HH + ct + l15) * HH + q * 8;
        const ushort* a2 = W + (size_t)(2 * HH + ct + l15) * HH + q * 8;
        for (int kt = 0; kt < 16; kt++) {
            bhalf8 b = *(const bhalf8*)&hst[((kt * 4 + q) * 16 + l15) * 8];
            acc[0] = MFMA16(ld8(a0), b, acc[0], 0, 0, 0); a0 += 32;
            acc[1] = MFMA16(ld8(a1), b, acc[1], 0, 0, 0); a1 += 32;
            acc[2] = MFMA16(ld8(a2), b, acc[2], 0, 0, 0); a2 += 32;
        }
    };

    auto gru_epi = [&](const floatx4 gi[3], const floatx4 gh[3], const float* bhh,
                       float (*hfl)[68], ushort* hnb, ushort* outs_t) {
        float4 bh_r = *(const float4*)&bhh[0 * HH + bcol];
        float4 bh_z = *(const float4*)&bhh[1 * HH + bcol];
        float4 bh_n = *(const float4*)&bhh[2 * HH + bcol];
        union { ushort s4[4]; unsigned long long u; } pk;
        const float* bhr = &bh_r.x; const float* bhz = &bh_z.x; const float* bhn = &bh_n.x;
#pragma unroll
        for (int i = 0; i < 4; i++) {
            float rg_ = sigmoidf_(gi[0][i] + gh[0][i] + bhr[i]);
            float zg = sigmoidf_(gi[1][i] + gh[1][i] + bhz[i]);
            float ng = tanhf(gi[2][i] + rg_ * (gh[2][i] + bhn[i]));
            float hn = (1.f - zg) * ng + zg * hfl[l15][lcol + i];
            hfl[l15][lcol + i] = hn;
            pk.s4[i] = f2bf(hn);
        }
        __hip_atomic_store((unsigned long long*)(hnb + (size_t)(row0 + l15) * HH + bcol), pk.u,
                           __ATOMIC_RELAXED, __HIP_MEMORY_SCOPE_AGENT);
        if (outs_t) *(unsigned long long*)(outs_t + (size_t)(row0 + l15) * HH + bcol) = pk.u;
    };

    // pred(tpred) from h1stage; all blocks compute full 96 cols (LDS-local)
    auto pred_part = [&](int tpred) {
        float* outt = P.out + (size_t)(TT + tpred) * BB * FF;
        for (int jt = w; jt < 6; jt += 4) {
            floatx4 pa = {};
            const ushort* apw = P.Wlinb + (size_t)(jt * 16 + l15) * HH + q * 8;
            for (int kt = 0; kt < 16; kt++) {
                bhalf8 b = *(const bhalf8*)&h1stage[((kt * 4 + q) * 16 + l15) * 8];
                pa = MFMA16(ld8(apw), b, pa, 0, 0, 0); apw += 32;
            }
            int fc = jt * 16 + q * 4;
            float4 bl = *(const float4*)&P.blin[fc];
            const float* blp = &bl.x;
            float4 vout;
            float* vo = &vout.x;
#pragma unroll
            for (int i = 0; i < 4; i++) {
                float v = pa[i] + blp[i] + predf[l15][fc + i];
                v *= maskl[l15][fc + i];
                predf[l15][fc + i] = v;
                predb[l15][fc + i] = f2bf(v);
                vo[i] = v;
            }
            if (cg == 0) *(float4*)&outt[(size_t)(row0 + l15) * FF + fc] = vout;
        }
    };

    // ---- encoder: phase s = L0(s) + L1(s-1) ----
    for (int s = 0; s <= TT; s++) {
        release();
        // PRE (stale, guaranteed by previous wait): h1(s-2) + its gh GEMM; Z0 loads
        floatx4 gh1[3] = {};
        floatx4 gi0z[3];
        if (s >= 1) {
            stage(P.h1buf + (1 - (s & 1)) * HSZ, h1stage);   // h1(s-2)
            __syncthreads();
            gemm3_lds(h1stage, P.Whh1b, gh1);
        }
        if (s < TT) {
            const ushort* zt = P.Z0 + ((size_t)s * BB + row0 + l15) * G3;
#pragma unroll
            for (int g = 0; g < 3; g++) {
                union { unsigned long long u; ushort s4[4]; } z;
                z.u = *(const unsigned long long*)(zt + g * HH + bcol);
#pragma unroll
                for (int i = 0; i < 4; i++) gi0z[g][i] = bf2f(z.s4[i]);
            }
        }
        wait_();
        // POST (fresh): h0(s-1)
        stage(P.h0buf + (s & 1) * HSZ, h0stage);
        __syncthreads();
        if (s < TT) {
            floatx4 gh0[3] = {};
            gemm3_lds(h0stage, P.Whh0b, gh0);
            gru_epi(gi0z, gh0, P.bhh0, h0f, P.h0buf + (1 - (s & 1)) * HSZ, nullptr);
        }
        if (s >= 1) {
            int t = s - 1;
            floatx4 gi1[3] = {};
            gemm3_lds(h0stage, P.Wih1b, gi1);
            float4 bi0 = *(const float4*)&P.bih1[0 * HH + bcol];
            float4 bi1 = *(const float4*)&P.bih1[1 * HH + bcol];
            float4 bi2 = *(const float4*)&P.bih1[2 * HH + bcol];
            const float* b0 = &bi0.x; const float* b1 = &bi1.x; const float* b2 = &bi2.x;
#pragma unroll
            for (int i = 0; i < 4; i++) { gi1[0][i] += b0[i]; gi1[1][i] += b1[i]; gi1[2][i] += b2[i]; }
            gru_epi(gi1, gh1, P.bhh1, h1f, P.h1buf + (s & 1) * HSZ, P.outs + (size_t)t * BB * HH);
        }
    }

    // ---- decoder: 2 phases per step ----
    for (int t = 0; t < TT; t++) {
        int pp = t & 1;
        // ---- phase A: pred(t-1) + L0(t) ----
        release();
        // PRE: stage h0(t-1) [stale] + gh0 GEMM + static Zpe/Zvel loads
        stage(P.h0buf + pp * HSZ, h0stage);
        __syncthreads();
        floatx4 gh0[3] = {};
        gemm3_lds(h0stage, P.Whh0b, gh0);
        floatx4 zadd[3];
        {
            const float* zp = P.Zpe + (size_t)t * G3;
#pragma unroll
            for (int g = 0; g < 3; g++) {
                float4 z4 = *(const float4*)&zp[g * HH + bcol];
                const float* zp4 = &z4.x;
#pragma unroll
                for (int i = 0; i < 4; i++) zadd[g][i] = zp4[i];
            }
            if (t == 0) {
                const float* zv = P.Zvel + (size_t)(row0 + l15) * G3;
#pragma unroll
                for (int g = 0; g < 3; g++) {
                    float4 z4 = *(const float4*)&zv[g * HH + bcol];
                    const float* zp4 = &z4.x;
#pragma unroll
                    for (int i = 0; i < 4; i++) zadd[g][i] += zp4[i];
                }
            }
        }
        wait_();
        // POST: stage h1(t-1) [fresh]; pred(t-1); gi0; epi h0(t)
        stage(P.h1buf + pp * HSZ, h1stage);
        __syncthreads();
        if (t > 0) {
            pred_part(t - 1);
            __syncthreads();
        }
        {
            floatx4 gi0[3] = {};
            if (t > 0) {
                const ushort* a0 = P.Wih0b + (size_t)(0 * HH + ct + l15) * RNN_IN + q * 8;
                const ushort* a1 = P.Wih0b + (size_t)(1 * HH + ct + l15) * RNN_IN + q * 8;
                const ushort* a2 = P.Wih0b + (size_t)(2 * HH + ct + l15) * RNN_IN + q * 8;
                for (int kt = 0; kt < 3; kt++) {
                    bhalf8 b = *(const bhalf8*)(&predb[l15][kt * 32 + q * 8]);
                    gi0[0] = MFMA16(ld8(a0), b, gi0[0], 0, 0, 0); a0 += 32;
                    gi0[1] = MFMA16(ld8(a1), b, gi0[1], 0, 0, 0); a1 += 32;
                    gi0[2] = MFMA16(ld8(a2), b, gi0[2], 0, 0, 0); a2 += 32;
                }
            }
#pragma unroll
            for (int g = 0; g < 3; g++)
#pragma unroll
                for (int i = 0; i < 4; i++) gi0[g][i] += zadd[g][i];
            gru_epi(gi0, gh0, P.bhh0, h0f, P.h0buf + (1 - pp) * HSZ, nullptr);
        }

        // ---- phase B: L1(t) ----
        release();
        // PRE: gh1 from h1stage (h1(t-1) already resident in LDS — no stage)
        floatx4 gh1[3] = {};
        gemm3_lds(h1stage, P.Whh1b, gh1);
        wait_();
        // POST: stage h0(t) [fresh]; gi1; epi h1(t)
        stage(P.h0buf + (1 - pp) * HSZ, h0stage);
        __syncthreads();
        {
            floatx4 gi1[3] = {};
            gemm3_lds(h0stage, P.Wih1b, gi1);
            float4 bi0 = *(const float4*)&P.bih1[0 * HH + bcol];
            float4 bi1 = *(const float4*)&P.bih1[1 * HH + bcol];
            float4 bi2 = *(const float4*)&P.bih1[2 * HH + bcol];
            const float* b0 = &bi0.x; const float* b1 = &bi1.x; const float* b2 = &bi2.x;
#pragma unroll
            for (int i = 0; i < 4; i++) { gi1[0][i] += b0[i]; gi1[1][i] += b1[i]; gi1[2][i] += b2[i]; }
            gru_epi(gi1, gh1, P.bhh1, h1f, P.h1buf + (1 - pp) * HSZ, nullptr);
        }
    }
    // tail: pred(49); h1(49) in h1buf[0]
    release();
    wait_();
    stage(P.h1buf + 0 * HSZ, h1stage);
    __syncthreads();
    pred_part(TT - 1);
}

// ================= host =================
extern "C" void kernel_launch(void* const* d_in, const int* in_sizes, int n_in,
                              void* d_out, int out_size, void* d_ws, size_t ws_size,
                              hipStream_t stream)
{
    const float* input = (const float*)d_in[0];
    const float* W_ih0 = (const float*)d_in[1];
    const float* W_hh0 = (const float*)d_in[2];
    const float* b_ih0 = (const float*)d_in[3];
    const float* b_hh0 = (const float*)d_in[4];
    const float* W_ih1 = (const float*)d_in[5];
    const float* W_hh1 = (const float*)d_in[6];
    const float* b_ih1 = (const float*)d_in[7];
    const float* b_hh1 = (const float*)d_in[8];
    const float* W_lin = (const float*)d_in[9];
    const float* b_lin = (const float*)d_in[10];
    float* out = (float*)d_out;

    char* ws = (char*)d_ws;
    size_t off = 0;
    auto alloc = [&](size_t bytes) -> char* {
        off = (off + 255) & ~(size_t)255;
        char* p = ws + off;
        off += bytes;
        return p;
    };

    ushort* Wih0b = (ushort*)alloc((size_t)G3 * RNN_IN * 2);
    ushort* Whh0b = (ushort*)alloc((size_t)G3 * HH * 2);
    ushort* Wih1b = (ushort*)alloc((size_t)G3 * HH * 2);
    ushort* Whh1b = (ushort*)alloc((size_t)G3 * HH * 2);
    ushort* Wlinb = (ushort*)alloc((size_t)FF * HH * 2);
    ushort* x_en  = (ushort*)alloc((size_t)TT * BB * RNN_IN * 2);
    ushort* Z0    = (ushort*)alloc((size_t)TT * BB * G3 * 2);
    ushort* outs  = (ushort*)alloc((size_t)TT * BB * HH * 2);
    float*  Zpe   = (float*)alloc((size_t)TT * G3 * 4);
    float*  Zvel  = (float*)alloc((size_t)BB * G3 * 4);
    float*  pe    = (float*)alloc((size_t)100 * FF * 4);
    float*  maskp = (float*)alloc((size_t)BB * FF * 4);
    ushort* hb    = (ushort*)alloc((size_t)4 * BB * HH * 2);   // h0buf[2] + h1buf[2]
    unsigned* bar = (unsigned*)alloc(8192 * 4);                // 128 slots x 256B
    (void)ws_size; (void)in_sizes; (void)n_in; (void)out_size;

    dim3 blk(256);

    prep_weights<<<dim3(512), blk, 0, stream>>>(W_ih0, W_hh0, W_ih1, W_hh1, W_lin,
                                                Wih0b, Whh0b, Wih1b, Whh1b, Wlinb);
    {
        int total = TT * BB * RNN_IN + BB * FF + 100 * FF + 4 * BB * HH + 8192;
        prep_misc<<<dim3((total + 255) / 256), blk, 0, stream>>>(
            input, pe, maskp, x_en, hb, bar);
    }
    gemm_z0<<<dim3(TT * BB / 64, G3 / 96), blk, 0, stream>>>(x_en, Wih0b, b_ih0, Z0);
    zpe_kernel<<<dim3((TT * G3 + 255) / 256), blk, 0, stream>>>(pe, W_ih0, b_ih0, Zpe);
    zvel_kernel<<<dim3((BB * G3 + 255) / 256), blk, 0, stream>>>(input, W_ih0, Zvel);

    PArgs P;
    P.Z0 = Z0; P.Wih0b = Wih0b; P.Whh0b = Whh0b; P.Wih1b = Wih1b; P.Whh1b = Whh1b; P.Wlinb = Wlinb;
    P.bhh0 = b_hh0; P.bih1 = b_ih1; P.bhh1 = b_hh1; P.blin = b_lin;
    P.Zpe = Zpe; P.Zvel = Zvel; P.maskp = maskp; P.input = input;
    P.h0buf = hb; P.h1buf = hb + 2 * HSZ;
    P.outs = outs; P.out = out; P.slots = bar;

    void* kargs[] = { &P };
    hipError_t e = hipLaunchCooperativeKernel((void*)persistent7, dim3(128), dim3(256), kargs, 0, stream);
    (void)e;

    gemm_out_enc<<<dim3(TT * BB / 64, 1), blk, 0, stream>>>(outs, Wlinb, b_lin, input, out);
}

// Round 13
// 2077.541 us; speedup vs baseline: 1.4862x; 1.4862x over previous
//
#include <hip/hip_runtime.h>
#include <math.h>

#define TT 50
#define BB 256
#define FF 96
#define HH 512
#define G3 1536
#define RNN_IN 288
#define HSZ (BB * HH)

typedef __attribute__((ext_vector_type(8))) short bhalf8;
typedef __attribute__((ext_vector_type(4))) float floatx4;
#define MFMA16 __builtin_amdgcn_mfma_f32_16x16x32_bf16

__device__ inline ushort f2bf(float f) {
    union { float f; unsigned u; } v; v.f = f;
    unsigned r = (v.u + 0x7FFFu + ((v.u >> 16) & 1u)) >> 16;
    return (ushort)r;
}
__device__ inline float bf2f(ushort h) {
    union { unsigned u; float f; } v; v.u = ((unsigned)h) << 16; return v.f;
}
__device__ inline bhalf8 ld8(const ushort* p) { return *(const bhalf8*)p; }
__device__ inline float sigmoidf_(float x) { return 1.f / (1.f + __expf(-x)); }

__device__ inline float pe_val(int pos, int d) {
    float dv = expf(-9.210340371976184f * (float)(d & ~1) / 96.0f);
    float a = (float)pos * dv;
    return (d & 1) ? cosf(a) : sinf(a);
}

// ---------------- prep: weight cast fp32 -> bf16 ----------------
__global__ __launch_bounds__(256) void prep_weights(
    const float* Wih0, const float* Whh0, const float* Wih1, const float* Whh1, const float* Wlin,
    ushort* dWih0, ushort* dWhh0, ushort* dWih1, ushort* dWhh1, ushort* dWlin)
{
    const int n0 = G3 * RNN_IN;
    const int n1 = G3 * HH;
    const int n2 = FF * HH;
    const int total = n0 + 3 * n1 + n2;
    for (int i = blockIdx.x * 256 + threadIdx.x; i < total; i += gridDim.x * 256) {
        int j = i;
        if (j < n0) { dWih0[j] = f2bf(Wih0[j]); continue; }
        j -= n0;
        if (j < n1) { dWhh0[j] = f2bf(Whh0[j]); continue; }
        j -= n1;
        if (j < n1) { dWih1[j] = f2bf(Wih1[j]); continue; }
        j -= n1;
        if (j < n1) { dWhh1[j] = f2bf(Whh1[j]); continue; }
        j -= n1;
        dWlin[j] = f2bf(Wlin[j]);
    }
}

// ---------------- prep: pe, mask, x_en, h init, slots zero ----------------
__global__ __launch_bounds__(256) void prep_misc(
    const float* __restrict__ input, float* pe, float* maskp, ushort* x_en,
    ushort* hb, unsigned* bar)
{
    int i = blockIdx.x * 256 + threadIdx.x;
    if (i < TT * BB * RNN_IN) {
        int t = i / (BB * RNN_IN);
        int r = i % (BB * RNN_IN);
        int b = r / RNN_IN, c = r % RNN_IN;
        float v;
        if (c < FF) v = input[(t * BB + b) * FF + c];
        else if (c < 2 * FF) {
            int cc = c - FF;
            v = (t == 0) ? 0.f : input[(t * BB + b) * FF + cc] - input[((t - 1) * BB + b) * FF + cc];
        } else v = pe_val(t, c - 2 * FF);
        x_en[i] = f2bf(v);
        return;
    }
    i -= TT * BB * RNN_IN;
    if (i < BB * FF) {
        int b = i / FF, f = i % FF;
        float mean = 0.f, sq = 0.f;
        for (int t = 0; t < TT; t++) {
            float x = input[(t * BB + b) * FF + f];
            mean += x; sq += x * x;
        }
        mean /= (float)TT;
        float var = (sq - (float)TT * mean * mean) / (float)(TT - 1);
        float sd = sqrtf(fmaxf(var, 0.f));
        maskp[i] = (sd > 1e-4f) ? 1.f : 0.f;
        return;
    }
    i -= BB * FF;
    if (i < 100 * FF) { pe[i] = pe_val(i / FF, i % FF); return; }
    i -= 100 * FF;
    if (i < 4 * BB * HH) { hb[i] = 0; return; }   // h0buf[2] + h1buf[2]
    i -= 4 * BB * HH;
    if (i < 16384) { bar[i] = 0; return; }         // 256 slots x 64 uints (256B lines)
}

// ---------------- Zpe: pe_dec part of decoder gi0 (+ b_ih0 folded) ----------------
__global__ __launch_bounds__(256) void zpe_kernel(
    const float* __restrict__ pe, const float* __restrict__ Wih0,
    const float* __restrict__ bih0, float* __restrict__ Zpe)
{
    int idx = blockIdx.x * 256 + threadIdx.x;
    if (idx >= TT * G3) return;
    int t = idx / G3, n = idx % G3;
    float s = bih0[n];
    const float* per = pe + (TT + t) * FF;
    const float* wr = Wih0 + n * RNN_IN + 2 * FF;
    for (int k = 0; k < FF; k++) s += per[k] * wr[k];
    Zpe[idx] = s;
}

// ---------------- Zvel0: input[0] + vel parts of decoder step-0 gi0 ----------------
__global__ __launch_bounds__(256) void zvel_kernel(
    const float* __restrict__ input, const float* __restrict__ Wih0, float* __restrict__ Zvel)
{
    int idx = blockIdx.x * 256 + threadIdx.x;
    if (idx >= BB * G3) return;
    int m = idx / G3, n = idx % G3;
    const float* a0 = input + m * FF;                       // input[0]
    const float* aL = input + (TT - 1) * BB * FF + m * FF;  // input[-1]
    const float* wr = Wih0 + n * RNN_IN;
    float s = 0.f;
    for (int k = 0; k < FF; k++) s += a0[k] * wr[k] + (a0[k] - aL[k]) * wr[FF + k];
    Zvel[idx] = s;
}

// ---------------- big GEMM: Z0[t][b][gatecol] = bf16(x_en @ Wih0^T + b_ih0) ----------------
__global__ __launch_bounds__(256) void gemm_z0(
    const ushort* __restrict__ A, const ushort* __restrict__ W,
    const float* __restrict__ bias, ushort* __restrict__ C)
{
    int lane = threadIdx.x & 63, w = threadIdx.x >> 6;
    int row0 = blockIdx.x * 64 + w * 16;
    int c0 = blockIdx.y * 96;
    int l15 = lane & 15, q = lane >> 4;
    const ushort* ap = A + (size_t)(row0 + l15) * RNN_IN + q * 8;
    floatx4 acc[6] = {};
    const ushort* wp[6];
#pragma unroll
    for (int j = 0; j < 6; j++) wp[j] = W + (size_t)(c0 + 16 * j + l15) * RNN_IN + q * 8;
    for (int kt = 0; kt < RNN_IN / 32; kt++) {
        bhalf8 a = ld8(ap + kt * 32);
#pragma unroll
        for (int j = 0; j < 6; j++) {
            bhalf8 b = ld8(wp[j] + kt * 32);
            acc[j] = MFMA16(a, b, acc[j], 0, 0, 0);
        }
    }
#pragma unroll
    for (int j = 0; j < 6; j++) {
        int col = c0 + 16 * j + l15;
        float bb = bias[col];
#pragma unroll
        for (int i = 0; i < 4; i++) {
            int r = row0 + q * 4 + i;
            C[(size_t)r * G3 + col] = f2bf(acc[j][i] + bb);
        }
    }
}

// ---------------- enc outputs: out = outs @ Wlin^T + b_lin + input ----------------
__global__ __launch_bounds__(256) void gemm_out_enc(
    const ushort* __restrict__ A, const ushort* __restrict__ W,
    const float* __restrict__ bias, const float* __restrict__ addsrc, float* __restrict__ out)
{
    int lane = threadIdx.x & 63, w = threadIdx.x >> 6;
    int row0 = blockIdx.x * 64 + w * 16;
    int l15 = lane & 15, q = lane >> 4;
    const ushort* ap = A + (size_t)(row0 + l15) * HH + q * 8;
    floatx4 acc[6] = {};
    const ushort* wp[6];
#pragma unroll
    for (int j = 0; j < 6; j++) wp[j] = W + (size_t)(16 * j + l15) * HH + q * 8;
    for (int kt = 0; kt < HH / 32; kt++) {
        bhalf8 a = ld8(ap + kt * 32);
#pragma unroll
        for (int j = 0; j < 6; j++) {
            bhalf8 b = ld8(wp[j] + kt * 32);
            acc[j] = MFMA16(a, b, acc[j], 0, 0, 0);
        }
    }
#pragma unroll
    for (int j = 0; j < 6; j++) {
        int col = 16 * j + l15;
        float bb = bias[col];
#pragma unroll
        for (int i = 0; i < 4; i++) {
            int r = row0 + q * 4 + i;
            out[(size_t)r * FF + col] = acc[j][i] + bb + addsrc[(size_t)r * FF + col];
        }
    }
}

// ================= persistent cooperative kernel =================
// r8 logic (split barrier, streamed W, proven atomic-load stage) scaled to
// FULL CHIP: 256 blocks x 128 threads (2 waves). rg = bid>>4 (16 row-groups
// of 16 rows), cg = bid&15 (16 col-groups of 32 h-cols). Under round-robin
// XCD dispatch, each XCD hosts only cgs {x, x+8} -> ~384 KB of W slices,
// fully L2-resident. Per-CU W-stream and MFMA work halve vs r8's
// 128-blocks-on-256-CUs. NO register-resident W (r10-r12 path abandoned).

struct PArgs {
    const ushort* Z0;         // [TT][BB][G3]
    const ushort* Wih0b;      // [G3][288]
    const ushort* Whh0b; const ushort* Wih1b; const ushort* Whh1b;  // [G3][512]
    const ushort* Wlinb;      // [96][512]
    const float* bhh0; const float* bih1; const float* bhh1; const float* blin;
    const float* Zpe;         // [TT][G3]
    const float* Zvel;        // [BB][G3]
    const float* maskp;       // [BB][96]
    const float* input;       // input[0] for pred init
    ushort* h0buf;            // [2][BB][HH]
    ushort* h1buf;            // [2][BB][HH]
    ushort* outs;             // [TT][BB][HH]
    float* out;
    unsigned* slots;          // 256 slots x 64 uints (256B lines)
};

__global__ __launch_bounds__(128) void persistent11(PArgs P)
{
    const int tid = threadIdx.x;
    const int w = tid >> 6;               // 0..1
    const int lane = tid & 63;
    const int l15 = lane & 15, q = lane >> 4;
    const int rg = blockIdx.x >> 4, cg = blockIdx.x & 15;
    const int row0 = rg * 16;
    const int ct = cg * 32 + w * 16;      // wave's 16-col base
    const int bcol = ct + q * 4;          // thread's first of 4 h-cols
    const int lcol = w * 16 + q * 4;      // within block's 32-col LDS slice

    __shared__ ushort h0stage[8192];      // [ktq][l15][8] B-frag order
    __shared__ ushort h1stage[8192];
    __shared__ float h0f[16][36];
    __shared__ float h1f[16][36];
    __shared__ float predf[16][100];
    __shared__ float maskl[16][100];
    __shared__ ushort predb[16][104];

    for (int i = tid; i < 16 * 36; i += 128) { ((float*)h0f)[i] = 0.f; ((float*)h1f)[i] = 0.f; }
    for (int i = tid; i < 16 * 96; i += 128) {
        int r = i / 96, c = i % 96;
        float p0 = P.input[(row0 + r) * FF + c];
        predf[r][c] = p0;
        predb[r][c] = f2bf(p0);
        maskl[r][c] = P.maskp[(row0 + r) * FF + c];
    }
    __syncthreads();

    unsigned phase = 0;
    unsigned* myslot = P.slots + (size_t)(rg * 16 + cg) * 64;
    const unsigned* pslot = P.slots + (size_t)(rg * 16 + (tid & 15)) * 64;

    // signal early: drain our stores, then publish phase
    auto release = [&]() {
        phase++;
        asm volatile("s_waitcnt vmcnt(0)" ::: "memory");
        __syncthreads();
        if (tid == 0)
            __hip_atomic_store(myslot, phase, __ATOMIC_RELAXED, __HIP_MEMORY_SCOPE_AGENT);
    };
    // wait late: poll partners
    auto wait_ = [&]() {
        if (tid < 16 && tid != cg) {
            while (__hip_atomic_load(pslot, __ATOMIC_RELAXED, __HIP_MEMORY_SCOPE_AGENT) < phase)
                __builtin_amdgcn_s_sleep(1);
        }
        __syncthreads();
        asm volatile("" ::: "memory");
    };

    // cooperative stage: 16 rows x 512 cols bf16 -> LDS [ktq][l15][8]
    // 128 threads: r = tid&15, cb = tid>>4 (8 col-blocks of 64 cols);
    // 16 x 8B agent-scope atomic loads per thread (r8's proven pattern).
    auto stage = [&](const ushort* src, ushort* dst) {
        const int r = tid & 15;
        const int cb = tid >> 4;
        const unsigned long long* gp =
            (const unsigned long long*)(src + (size_t)(row0 + r) * HH + cb * 64);
        unsigned long long v[16];
#pragma unroll
        for (int j = 0; j < 16; j++)
            v[j] = __hip_atomic_load(gp + j, __ATOMIC_RELAXED, __HIP_MEMORY_SCOPE_AGENT);
#pragma unroll
        for (int qq = 0; qq < 8; qq++) {
            unsigned long long* lp = (unsigned long long*)(dst + ((cb * 8 + qq) * 16 + r) * 8);
            lp[0] = v[2 * qq];
            lp[1] = v[2 * qq + 1];
        }
    };

    // 3-gate GEMM: A=W rows (plain L2 loads), B=h from staged LDS
    auto gemm3_lds = [&](const ushort* hst, const ushort* W, floatx4 acc[3]) {
        const ushort* a0 = W + (size_t)(0 * HH + ct + l15) * HH + q * 8;
        const ushort* a1 = W + (size_t)(1 * HH + ct + l15) * HH + q * 8;
        const ushort* a2 = W + (size_t)(2 * HH + ct + l15) * HH + q * 8;
        for (int kt = 0; kt < 16; kt++) {
            bhalf8 b = *(const bhalf8*)&hst[((kt * 4 + q) * 16 + l15) * 8];
            acc[0] = MFMA16(ld8(a0), b, acc[0], 0, 0, 0); a0 += 32;
            acc[1] = MFMA16(ld8(a1), b, acc[1], 0, 0, 0); a1 += 32;
            acc[2] = MFMA16(ld8(a2), b, acc[2], 0, 0, 0); a2 += 32;
        }
    };

    auto gru_epi = [&](const floatx4 gi[3], const floatx4 gh[3], const float* bhh,
                       float (*hfl)[36], ushort* hnb, ushort* outs_t) {
        float4 bh_r = *(const float4*)&bhh[0 * HH + bcol];
        float4 bh_z = *(const float4*)&bhh[1 * HH + bcol];
        float4 bh_n = *(const float4*)&bhh[2 * HH + bcol];
        union { ushort s4[4]; unsigned long long u; } pk;
        const float* bhr = &bh_r.x; const float* bhz = &bh_z.x; const float* bhn = &bh_n.x;
#pragma unroll
        for (int i = 0; i < 4; i++) {
            float rg_ = sigmoidf_(gi[0][i] + gh[0][i] + bhr[i]);
            float zg = sigmoidf_(gi[1][i] + gh[1][i] + bhz[i]);
            float ng = tanhf(gi[2][i] + rg_ * (gh[2][i] + bhn[i]));
            float hn = (1.f - zg) * ng + zg * hfl[l15][lcol + i];
            hfl[l15][lcol + i] = hn;
            pk.s4[i] = f2bf(hn);
        }
        __hip_atomic_store((unsigned long long*)(hnb + (size_t)(row0 + l15) * HH + bcol), pk.u,
                           __ATOMIC_RELAXED, __HIP_MEMORY_SCOPE_AGENT);
        if (outs_t) *(unsigned long long*)(outs_t + (size_t)(row0 + l15) * HH + bcol) = pk.u;
    };

    // pred(tpred) from h1stage; all blocks compute full 96 cols (LDS-local)
    auto pred_part = [&](int tpred) {
        float* outt = P.out + (size_t)(TT + tpred) * BB * FF;
        for (int jt = w; jt < 6; jt += 2) {
            floatx4 pa = {};
            const ushort* apw = P.Wlinb + (size_t)(jt * 16 + l15) * HH + q * 8;
            for (int kt = 0; kt < 16; kt++) {
                bhalf8 b = *(const bhalf8*)&h1stage[((kt * 4 + q) * 16 + l15) * 8];
                pa = MFMA16(ld8(apw), b, pa, 0, 0, 0); apw += 32;
            }
            int fc = jt * 16 + q * 4;
            float4 bl = *(const float4*)&P.blin[fc];
            const float* blp = &bl.x;
            float4 vout;
            float* vo = &vout.x;
#pragma unroll
            for (int i = 0; i < 4; i++) {
                float v = pa[i] + blp[i] + predf[l15][fc + i];
                v *= maskl[l15][fc + i];
                predf[l15][fc + i] = v;
                predb[l15][fc + i] = f2bf(v);
                vo[i] = v;
            }
            if (cg == 0) *(float4*)&outt[(size_t)(row0 + l15) * FF + fc] = vout;
        }
    };

    // ---- encoder: phase s = L0(s) + L1(s-1) ----
    for (int s = 0; s <= TT; s++) {
        release();
        // PRE (stale): h1(s-2) stage + gh1 GEMM; Z0 loads
        floatx4 gh1[3] = {};
        floatx4 gi0z[3];
        if (s >= 1) {
            stage(P.h1buf + (1 - (s & 1)) * HSZ, h1stage);
            __syncthreads();
            gemm3_lds(h1stage, P.Whh1b, gh1);
        }
        if (s < TT) {
            const ushort* zt = P.Z0 + ((size_t)s * BB + row0 + l15) * G3;
#pragma unroll
            for (int g = 0; g < 3; g++) {
                union { unsigned long long u; ushort s4[4]; } z;
                z.u = *(const unsigned long long*)(zt + g * HH + bcol);
#pragma unroll
                for (int i = 0; i < 4; i++) gi0z[g][i] = bf2f(z.s4[i]);
            }
        }
        wait_();
        // POST (fresh): h0(s-1)
        stage(P.h0buf + (s & 1) * HSZ, h0stage);
        __syncthreads();
        if (s < TT) {
            floatx4 gh0[3] = {};
            gemm3_lds(h0stage, P.Whh0b, gh0);
            gru_epi(gi0z, gh0, P.bhh0, h0f, P.h0buf + (1 - (s & 1)) * HSZ, nullptr);
        }
        if (s >= 1) {
            int t = s - 1;
            floatx4 gi1[3] = {};
            gemm3_lds(h0stage, P.Wih1b, gi1);
            float4 bi0 = *(const float4*)&P.bih1[0 * HH + bcol];
            float4 bi1 = *(const float4*)&P.bih1[1 * HH + bcol];
            float4 bi2 = *(const float4*)&P.bih1[2 * HH + bcol];
            const float* b0 = &bi0.x; const float* b1 = &bi1.x; const float* b2 = &bi2.x;
#pragma unroll
            for (int i = 0; i < 4; i++) { gi1[0][i] += b0[i]; gi1[1][i] += b1[i]; gi1[2][i] += b2[i]; }
            gru_epi(gi1, gh1, P.bhh1, h1f, P.h1buf + (s & 1) * HSZ, P.outs + (size_t)t * BB * HH);
        }
    }

    // ---- decoder: 2 phases per step ----
    for (int t = 0; t < TT; t++) {
        int pp = t & 1;
        // ---- phase A: pred(t-1) + L0(t) ----
        release();
        // PRE: stage h0(t-1) [stale]; gh0; Zpe/Zvel loads
        stage(P.h0buf + pp * HSZ, h0stage);
        __syncthreads();
        floatx4 gh0[3] = {};
        gemm3_lds(h0stage, P.Whh0b, gh0);
        floatx4 zadd[3];
        {
            const float* zp = P.Zpe + (size_t)t * G3;
#pragma unroll
            for (int g = 0; g < 3; g++) {
                float4 z4 = *(const float4*)&zp[g * HH + bcol];
                const float* zp4 = &z4.x;
#pragma unroll
                for (int i = 0; i < 4; i++) zadd[g][i] = zp4[i];
            }
            if (t == 0) {
                const float* zv = P.Zvel + (size_t)(row0 + l15) * G3;
#pragma unroll
                for (int g = 0; g < 3; g++) {
                    float4 z4 = *(const float4*)&zv[g * HH + bcol];
                    const float* zp4 = &z4.x;
#pragma unroll
                    for (int i = 0; i < 4; i++) zadd[g][i] += zp4[i];
                }
            }
        }
        wait_();
        // POST: stage h1(t-1) [fresh]; pred(t-1); gi0; epi h0(t)
        stage(P.h1buf + pp * HSZ, h1stage);
        __syncthreads();
        if (t > 0) {
            pred_part(t - 1);
            __syncthreads();
        }
        {
            floatx4 gi0[3] = {};
            if (t > 0) {
                const ushort* a0 = P.Wih0b + (size_t)(0 * HH + ct + l15) * RNN_IN + q * 8;
                const ushort* a1 = P.Wih0b + (size_t)(1 * HH + ct + l15) * RNN_IN + q * 8;
                const ushort* a2 = P.Wih0b + (size_t)(2 * HH + ct + l15) * RNN_IN + q * 8;
                for (int kt = 0; kt < 3; kt++) {
                    bhalf8 b = *(const bhalf8*)(&predb[l15][kt * 32 + q * 8]);
                    gi0[0] = MFMA16(ld8(a0), b, gi0[0], 0, 0, 0); a0 += 32;
                    gi0[1] = MFMA16(ld8(a1), b, gi0[1], 0, 0, 0); a1 += 32;
                    gi0[2] = MFMA16(ld8(a2), b, gi0[2], 0, 0, 0); a2 += 32;
                }
            }
#pragma unroll
            for (int g = 0; g < 3; g++)
#pragma unroll
                for (int i = 0; i < 4; i++) gi0[g][i] += zadd[g][i];
            gru_epi(gi0, gh0, P.bhh0, h0f, P.h0buf + (1 - pp) * HSZ, nullptr);
        }

        // ---- phase B: L1(t) ----
        release();
        // PRE: gh1 from resident h1stage (no re-stage)
        floatx4 gh1[3] = {};
        gemm3_lds(h1stage, P.Whh1b, gh1);
        wait_();
        // POST: stage h0(t) [fresh]; gi1; epi h1(t)
        stage(P.h0buf + (1 - pp) * HSZ, h0stage);
        __syncthreads();
        {
            floatx4 gi1[3] = {};
            gemm3_lds(h0stage, P.Wih1b, gi1);
            float4 bi0 = *(const float4*)&P.bih1[0 * HH + bcol];
            float4 bi1 = *(const float4*)&P.bih1[1 * HH + bcol];
            float4 bi2 = *(const float4*)&P.bih1[2 * HH + bcol];
            const float* b0 = &bi0.x; const float* b1 = &bi1.x; const float* b2 = &bi2.x;
#pragma unroll
            for (int i = 0; i < 4; i++) { gi1[0][i] += b0[i]; gi1[1][i] += b1[i]; gi1[2][i] += b2[i]; }
            gru_epi(gi1, gh1, P.bhh1, h1f, P.h1buf + (1 - pp) * HSZ, nullptr);
        }
    }
    // tail: pred(49); h1(49) in h1buf[0]
    release();
    wait_();
    stage(P.h1buf + 0 * HSZ, h1stage);
    __syncthreads();
    pred_part(TT - 1);
}

// ================= host =================
extern "C" void kernel_launch(void* const* d_in, const int* in_sizes, int n_in,
                              void* d_out, int out_size, void* d_ws, size_t ws_size,
                              hipStream_t stream)
{
    const float* input = (const float*)d_in[0];
    const float* W_ih0 = (const float*)d_in[1];
    const float* W_hh0 = (const float*)d_in[2];
    const float* b_ih0 = (const float*)d_in[3];
    const float* b_hh0 = (const float*)d_in[4];
    const float* W_ih1 = (const float*)d_in[5];
    const float* W_hh1 = (const float*)d_in[6];
    const float* b_ih1 = (const float*)d_in[7];
    const float* b_hh1 = (const float*)d_in[8];
    const float* W_lin = (const float*)d_in[9];
    const float* b_lin = (const float*)d_in[10];
    float* out = (float*)d_out;

    char* ws = (char*)d_ws;
    size_t off = 0;
    auto alloc = [&](size_t bytes) -> char* {
        off = (off + 255) & ~(size_t)255;
        char* p = ws + off;
        off += bytes;
        return p;
    };

    ushort* Wih0b = (ushort*)alloc((size_t)G3 * RNN_IN * 2);
    ushort* Whh0b = (ushort*)alloc((size_t)G3 * HH * 2);
    ushort* Wih1b = (ushort*)alloc((size_t)G3 * HH * 2);
    ushort* Whh1b = (ushort*)alloc((size_t)G3 * HH * 2);
    ushort* Wlinb = (ushort*)alloc((size_t)FF * HH * 2);
    ushort* x_en  = (ushort*)alloc((size_t)TT * BB * RNN_IN * 2);
    ushort* Z0    = (ushort*)alloc((size_t)TT * BB * G3 * 2);
    ushort* outs  = (ushort*)alloc((size_t)TT * BB * HH * 2);
    float*  Zpe   = (float*)alloc((size_t)TT * G3 * 4);
    float*  Zvel  = (float*)alloc((size_t)BB * G3 * 4);
    float*  pe    = (float*)alloc((size_t)100 * FF * 4);
    float*  maskp = (float*)alloc((size_t)BB * FF * 4);
    ushort* hb    = (ushort*)alloc((size_t)4 * BB * HH * 2);   // h0buf[2] + h1buf[2]
    unsigned* bar = (unsigned*)alloc(16384 * 4);               // 256 slots x 256B
    (void)ws_size; (void)in_sizes; (void)n_in; (void)out_size;

    dim3 blk(256);

    prep_weights<<<dim3(512), blk, 0, stream>>>(W_ih0, W_hh0, W_ih1, W_hh1, W_lin,
                                                Wih0b, Whh0b, Wih1b, Whh1b, Wlinb);
    {
        int total = TT * BB * RNN_IN + BB * FF + 100 * FF + 4 * BB * HH + 16384;
        prep_misc<<<dim3((total + 255) / 256), blk, 0, stream>>>(
            input, pe, maskp, x_en, hb, bar);
    }
    gemm_z0<<<dim3(TT * BB / 64, G3 / 96), blk, 0, stream>>>(x_en, Wih0b, b_ih0, Z0);
    zpe_kernel<<<dim3((TT * G3 + 255) / 256), blk, 0, stream>>>(pe, W_ih0, b_ih0, Zpe);
    zvel_kernel<<<dim3((BB * G3 + 255) / 256), blk, 0, stream>>>(input, W_ih0, Zvel);

    PArgs P;
    P.Z0 = Z0; P.Wih0b = Wih0b; P.Whh0b = Whh0b; P.Wih1b = Wih1b; P.Whh1b = Whh1b; P.Wlinb = Wlinb;
    P.bhh0 = b_hh0; P.bih1 = b_ih1; P.bhh1 = b_hh1; P.blin = b_lin;
    P.Zpe = Zpe; P.Zvel = Zvel; P.maskp = maskp; P.input = input;
    P.h0buf = hb; P.h1buf = hb + 2 * HSZ;
    P.outs = outs; P.out = out; P.slots = bar;

    void* kargs[] = { &P };
    hipError_t e = hipLaunchCooperativeKernel((void*)persistent11, dim3(256), dim3(128), kargs, 0, stream);
    (void)e;

    gemm_out_enc<<<dim3(TT * BB / 64, 1), blk, 0, stream>>>(outs, Wlinb, b_lin, input, out);
}

// Round 14
// 1891.306 us; speedup vs baseline: 1.6325x; 1.0985x over previous
//
#include <hip/hip_runtime.h>
#include <math.h>

#define TT 50
#define BB 256
#define FF 96
#define HH 512
#define G3 1536
#define RNN_IN 288
#define HSZ (BB * HH)

typedef __attribute__((ext_vector_type(8))) short bhalf8;
typedef __attribute__((ext_vector_type(4))) float floatx4;
#define MFMA16 __builtin_amdgcn_mfma_f32_16x16x32_bf16

__device__ inline ushort f2bf(float f) {
    union { float f; unsigned u; } v; v.f = f;
    unsigned r = (v.u + 0x7FFFu + ((v.u >> 16) & 1u)) >> 16;
    return (ushort)r;
}
__device__ inline float bf2f(ushort h) {
    union { unsigned u; float f; } v; v.u = ((unsigned)h) << 16; return v.f;
}
__device__ inline bhalf8 ld8(const ushort* p) { return *(const bhalf8*)p; }
__device__ inline float sigmoidf_(float x) { return 1.f / (1.f + __expf(-x)); }

__device__ inline float pe_val(int pos, int d) {
    float dv = expf(-9.210340371976184f * (float)(d & ~1) / 96.0f);
    float a = (float)pos * dv;
    return (d & 1) ? cosf(a) : sinf(a);
}

// ---------------- prep: weight cast fp32 -> bf16 ----------------
__global__ __launch_bounds__(256) void prep_weights(
    const float* Wih0, const float* Whh0, const float* Wih1, const float* Whh1, const float* Wlin,
    ushort* dWih0, ushort* dWhh0, ushort* dWih1, ushort* dWhh1, ushort* dWlin)
{
    const int n0 = G3 * RNN_IN;
    const int n1 = G3 * HH;
    const int n2 = FF * HH;
    const int total = n0 + 3 * n1 + n2;
    for (int i = blockIdx.x * 256 + threadIdx.x; i < total; i += gridDim.x * 256) {
        int j = i;
        if (j < n0) { dWih0[j] = f2bf(Wih0[j]); continue; }
        j -= n0;
        if (j < n1) { dWhh0[j] = f2bf(Whh0[j]); continue; }
        j -= n1;
        if (j < n1) { dWih1[j] = f2bf(Wih1[j]); continue; }
        j -= n1;
        if (j < n1) { dWhh1[j] = f2bf(Whh1[j]); continue; }
        j -= n1;
        dWlin[j] = f2bf(Wlin[j]);
    }
}

// ---------------- prep: pe, mask, x_en, h init, slots zero ----------------
__global__ __launch_bounds__(256) void prep_misc(
    const float* __restrict__ input, float* pe, float* maskp, ushort* x_en,
    ushort* hb, unsigned* bar)
{
    int i = blockIdx.x * 256 + threadIdx.x;
    if (i < TT * BB * RNN_IN) {
        int t = i / (BB * RNN_IN);
        int r = i % (BB * RNN_IN);
        int b = r / RNN_IN, c = r % RNN_IN;
        float v;
        if (c < FF) v = input[(t * BB + b) * FF + c];
        else if (c < 2 * FF) {
            int cc = c - FF;
            v = (t == 0) ? 0.f : input[(t * BB + b) * FF + cc] - input[((t - 1) * BB + b) * FF + cc];
        } else v = pe_val(t, c - 2 * FF);
        x_en[i] = f2bf(v);
        return;
    }
    i -= TT * BB * RNN_IN;
    if (i < BB * FF) {
        int b = i / FF, f = i % FF;
        float mean = 0.f, sq = 0.f;
        for (int t = 0; t < TT; t++) {
            float x = input[(t * BB + b) * FF + f];
            mean += x; sq += x * x;
        }
        mean /= (float)TT;
        float var = (sq - (float)TT * mean * mean) / (float)(TT - 1);
        float sd = sqrtf(fmaxf(var, 0.f));
        maskp[i] = (sd > 1e-4f) ? 1.f : 0.f;
        return;
    }
    i -= BB * FF;
    if (i < 100 * FF) { pe[i] = pe_val(i / FF, i % FF); return; }
    i -= 100 * FF;
    if (i < 4 * BB * HH) { hb[i] = 0; return; }   // h0buf[2] + h1buf[2]
    i -= 4 * BB * HH;
    if (i < 16384) { bar[i] = 0; return; }         // 256 slots x 64 uints (256B lines)
}

// ---------------- Zpe: pe_dec part of decoder gi0 (+ b_ih0 folded) ----------------
__global__ __launch_bounds__(256) void zpe_kernel(
    const float* __restrict__ pe, const float* __restrict__ Wih0,
    const float* __restrict__ bih0, float* __restrict__ Zpe)
{
    int idx = blockIdx.x * 256 + threadIdx.x;
    if (idx >= TT * G3) return;
    int t = idx / G3, n = idx % G3;
    float s = bih0[n];
    const float* per = pe + (TT + t) * FF;
    const float* wr = Wih0 + n * RNN_IN + 2 * FF;
    for (int k = 0; k < FF; k++) s += per[k] * wr[k];
    Zpe[idx] = s;
}

// ---------------- Zvel0: input[0] + vel parts of decoder step-0 gi0 ----------------
__global__ __launch_bounds__(256) void zvel_kernel(
    const float* __restrict__ input, const float* __restrict__ Wih0, float* __restrict__ Zvel)
{
    int idx = blockIdx.x * 256 + threadIdx.x;
    if (idx >= BB * G3) return;
    int m = idx / G3, n = idx % G3;
    const float* a0 = input + m * FF;                       // input[0]
    const float* aL = input + (TT - 1) * BB * FF + m * FF;  // input[-1]
    const float* wr = Wih0 + n * RNN_IN;
    float s = 0.f;
    for (int k = 0; k < FF; k++) s += a0[k] * wr[k] + (a0[k] - aL[k]) * wr[FF + k];
    Zvel[idx] = s;
}

// ---------------- big GEMM: Z0[t][b][gatecol] = bf16(x_en @ Wih0^T + b_ih0) ----------------
__global__ __launch_bounds__(256) void gemm_z0(
    const ushort* __restrict__ A, const ushort* __restrict__ W,
    const float* __restrict__ bias, ushort* __restrict__ C)
{
    int lane = threadIdx.x & 63, w = threadIdx.x >> 6;
    int row0 = blockIdx.x * 64 + w * 16;
    int c0 = blockIdx.y * 96;
    int l15 = lane & 15, q = lane >> 4;
    const ushort* ap = A + (size_t)(row0 + l15) * RNN_IN + q * 8;
    floatx4 acc[6] = {};
    const ushort* wp[6];
#pragma unroll
    for (int j = 0; j < 6; j++) wp[j] = W + (size_t)(c0 + 16 * j + l15) * RNN_IN + q * 8;
    for (int kt = 0; kt < RNN_IN / 32; kt++) {
        bhalf8 a = ld8(ap + kt * 32);
#pragma unroll
        for (int j = 0; j < 6; j++) {
            bhalf8 b = ld8(wp[j] + kt * 32);
            acc[j] = MFMA16(a, b, acc[j], 0, 0, 0);
        }
    }
#pragma unroll
    for (int j = 0; j < 6; j++) {
        int col = c0 + 16 * j + l15;
        float bb = bias[col];
#pragma unroll
        for (int i = 0; i < 4; i++) {
            int r = row0 + q * 4 + i;
            C[(size_t)r * G3 + col] = f2bf(acc[j][i] + bb);
        }
    }
}

// ---------------- enc outputs: out = outs @ Wlin^T + b_lin + input ----------------
__global__ __launch_bounds__(256) void gemm_out_enc(
    const ushort* __restrict__ A, const ushort* __restrict__ W,
    const float* __restrict__ bias, const float* __restrict__ addsrc, float* __restrict__ out)
{
    int lane = threadIdx.x & 63, w = threadIdx.x >> 6;
    int row0 = blockIdx.x * 64 + w * 16;
    int l15 = lane & 15, q = lane >> 4;
    const ushort* ap = A + (size_t)(row0 + l15) * HH + q * 8;
    floatx4 acc[6] = {};
    const ushort* wp[6];
#pragma unroll
    for (int j = 0; j < 6; j++) wp[j] = W + (size_t)(16 * j + l15) * HH + q * 8;
    for (int kt = 0; kt < HH / 32; kt++) {
        bhalf8 a = ld8(ap + kt * 32);
#pragma unroll
        for (int j = 0; j < 6; j++) {
            bhalf8 b = ld8(wp[j] + kt * 32);
            acc[j] = MFMA16(a, b, acc[j], 0, 0, 0);
        }
    }
#pragma unroll
    for (int j = 0; j < 6; j++) {
        int col = 16 * j + l15;
        float bb = bias[col];
#pragma unroll
        for (int i = 0; i < 4; i++) {
            int r = row0 + q * 4 + i;
            out[(size_t)r * FF + col] = acc[j][i] + bb + addsrc[(size_t)r * FF + col];
        }
    }
}

// ================= persistent cooperative kernel =================
// r13 sync structure, 256 blocks x 256 THREADS (4 waves/CU). Wave-pair
// specialization: waves 0-1 (wp=0) own the L0 stream (gh0, Z0/Zpe, gi0,
// h0 epilogue); waves 2-3 (wp=1) own the L1 stream (gh1, gi1, h1 epilogue,
// pred). Both pairs cover the same 32 cols for their layer. The two GEMM
// streams of each phase now run CONCURRENTLY on separate SIMDs; no
// accumulator crosses pairs (only LDS stage buffers + predb, guarded by
// __syncthreads).

struct PArgs {
    const ushort* Z0;         // [TT][BB][G3]
    const ushort* Wih0b;      // [G3][288]
    const ushort* Whh0b; const ushort* Wih1b; const ushort* Whh1b;  // [G3][512]
    const ushort* Wlinb;      // [96][512]
    const float* bhh0; const float* bih1; const float* bhh1; const float* blin;
    const float* Zpe;         // [TT][G3]
    const float* Zvel;        // [BB][G3]
    const float* maskp;       // [BB][96]
    const float* input;       // input[0] for pred init
    ushort* h0buf;            // [2][BB][HH]
    ushort* h1buf;            // [2][BB][HH]
    ushort* outs;             // [TT][BB][HH]
    float* out;
    unsigned* slots;          // 256 slots x 64 uints (256B lines)
};

__global__ __launch_bounds__(256) void persistent12(PArgs P)
{
    const int tid = threadIdx.x;
    const int w = tid >> 6;               // 0..3
    const int wp = w >> 1;                // wave-pair: 0 = L0 stream, 1 = L1 stream
    const int wi = w & 1;                 // index within pair
    const int lane = tid & 63;
    const int l15 = lane & 15, q = lane >> 4;
    const int rg = blockIdx.x >> 4, cg = blockIdx.x & 15;
    const int row0 = rg * 16;
    const int ct = cg * 32 + wi * 16;     // wave's 16-col base (same for both pairs)
    const int bcol = ct + q * 4;          // thread's first of 4 h-cols
    const int lcol = wi * 16 + q * 4;     // within block's 32-col LDS slice

    __shared__ ushort h0stage[8192];      // [ktq][l15][8] B-frag order
    __shared__ ushort h1stage[8192];
    __shared__ float h0f[16][36];         // owned by wp0
    __shared__ float h1f[16][36];         // owned by wp1
    __shared__ float predf[16][100];      // owned by wp1
    __shared__ float maskl[16][100];
    __shared__ ushort predb[16][104];     // written wp1, read wp0

    for (int i = tid; i < 16 * 36; i += 256) { ((float*)h0f)[i] = 0.f; ((float*)h1f)[i] = 0.f; }
    for (int i = tid; i < 16 * 96; i += 256) {
        int r = i / 96, c = i % 96;
        float p0 = P.input[(row0 + r) * FF + c];
        predf[r][c] = p0;
        predb[r][c] = f2bf(p0);
        maskl[r][c] = P.maskp[(row0 + r) * FF + c];
    }
    __syncthreads();

    unsigned phase = 0;
    unsigned* myslot = P.slots + (size_t)(rg * 16 + cg) * 64;
    const unsigned* pslot = P.slots + (size_t)(rg * 16 + (tid & 15)) * 64;

    // signal early: drain our stores, then publish phase
    auto release = [&]() {
        phase++;
        asm volatile("s_waitcnt vmcnt(0)" ::: "memory");
        __syncthreads();
        if (tid == 0)
            __hip_atomic_store(myslot, phase, __ATOMIC_RELAXED, __HIP_MEMORY_SCOPE_AGENT);
    };
    // wait late: poll partners
    auto wait_ = [&]() {
        if (tid < 16 && tid != cg) {
            while (__hip_atomic_load(pslot, __ATOMIC_RELAXED, __HIP_MEMORY_SCOPE_AGENT) < phase)
                __builtin_amdgcn_s_sleep(1);
        }
        __syncthreads();
        asm volatile("" ::: "memory");
    };

    // cooperative stage (256 threads): 16 rows x 512 cols bf16 -> LDS
    // [ktq][l15][8]; 8 x 8B agent-scope atomic loads per thread (r8-proven).
    auto stage = [&](const ushort* src, ushort* dst) {
        const int r = tid & 15;
        const int cb = tid >> 4;          // 16 col-blocks of 32 cols
        const unsigned long long* gp =
            (const unsigned long long*)(src + (size_t)(row0 + r) * HH + cb * 32);
        unsigned long long v[8];
#pragma unroll
        for (int j = 0; j < 8; j++)
            v[j] = __hip_atomic_load(gp + j, __ATOMIC_RELAXED, __HIP_MEMORY_SCOPE_AGENT);
#pragma unroll
        for (int qq = 0; qq < 4; qq++) {
            unsigned long long* lp = (unsigned long long*)(dst + ((cb * 4 + qq) * 16 + r) * 8);
            lp[0] = v[2 * qq];
            lp[1] = v[2 * qq + 1];
        }
    };

    // 3-gate GEMM: A=W rows (plain L2 loads), B=h from staged LDS
    auto gemm3_lds = [&](const ushort* hst, const ushort* W, floatx4 acc[3]) {
        const ushort* a0 = W + (size_t)(0 * HH + ct + l15) * HH + q * 8;
        const ushort* a1 = W + (size_t)(1 * HH + ct + l15) * HH + q * 8;
        const ushort* a2 = W + (size_t)(2 * HH + ct + l15) * HH + q * 8;
        for (int kt = 0; kt < 16; kt++) {
            bhalf8 b = *(const bhalf8*)&hst[((kt * 4 + q) * 16 + l15) * 8];
            acc[0] = MFMA16(ld8(a0), b, acc[0], 0, 0, 0); a0 += 32;
            acc[1] = MFMA16(ld8(a1), b, acc[1], 0, 0, 0); a1 += 32;
            acc[2] = MFMA16(ld8(a2), b, acc[2], 0, 0, 0); a2 += 32;
        }
    };

    auto gru_epi = [&](const floatx4 gi[3], const floatx4 gh[3], const float* bhh,
                       float (*hfl)[36], ushort* hnb, ushort* outs_t) {
        float4 bh_r = *(const float4*)&bhh[0 * HH + bcol];
        float4 bh_z = *(const float4*)&bhh[1 * HH + bcol];
        float4 bh_n = *(const float4*)&bhh[2 * HH + bcol];
        union { ushort s4[4]; unsigned long long u; } pk;
        const float* bhr = &bh_r.x; const float* bhz = &bh_z.x; const float* bhn = &bh_n.x;
#pragma unroll
        for (int i = 0; i < 4; i++) {
            float rg_ = sigmoidf_(gi[0][i] + gh[0][i] + bhr[i]);
            float zg = sigmoidf_(gi[1][i] + gh[1][i] + bhz[i]);
            float ng = tanhf(gi[2][i] + rg_ * (gh[2][i] + bhn[i]));
            float hn = (1.f - zg) * ng + zg * hfl[l15][lcol + i];
            hfl[l15][lcol + i] = hn;
            pk.s4[i] = f2bf(hn);
        }
        __hip_atomic_store((unsigned long long*)(hnb + (size_t)(row0 + l15) * HH + bcol), pk.u,
                           __ATOMIC_RELAXED, __HIP_MEMORY_SCOPE_AGENT);
        if (outs_t) *(unsigned long long*)(outs_t + (size_t)(row0 + l15) * HH + bcol) = pk.u;
    };

    // pred(tpred) from h1stage; run by wp1's two waves (full 96 cols)
    auto pred_part = [&](int tpred) {
        float* outt = P.out + (size_t)(TT + tpred) * BB * FF;
        for (int jt = wi; jt < 6; jt += 2) {
            floatx4 pa = {};
            const ushort* apw = P.Wlinb + (size_t)(jt * 16 + l15) * HH + q * 8;
            for (int kt = 0; kt < 16; kt++) {
                bhalf8 b = *(const bhalf8*)&h1stage[((kt * 4 + q) * 16 + l15) * 8];
                pa = MFMA16(ld8(apw), b, pa, 0, 0, 0); apw += 32;
            }
            int fc = jt * 16 + q * 4;
            float4 bl = *(const float4*)&P.blin[fc];
            const float* blp = &bl.x;
            float4 vout;
            float* vo = &vout.x;
#pragma unroll
            for (int i = 0; i < 4; i++) {
                float v = pa[i] + blp[i] + predf[l15][fc + i];
                v *= maskl[l15][fc + i];
                predf[l15][fc + i] = v;
                predb[l15][fc + i] = f2bf(v);
                vo[i] = v;
            }
            if (cg == 0) *(float4*)&outt[(size_t)(row0 + l15) * FF + fc] = vout;
        }
    };

    // ---- encoder: phase s = L0(s) [wp0] + L1(s-1) [wp1], concurrent ----
    for (int s = 0; s <= TT; s++) {
        release();
        // PRE: stage h1(s-2) [stale]; wp1: gh1; wp0: Z0 loads
        if (s >= 1) stage(P.h1buf + (1 - (s & 1)) * HSZ, h1stage);
        __syncthreads();
        floatx4 gh1[3] = {};
        floatx4 gi0z[3];
        if (wp == 1 && s >= 1) gemm3_lds(h1stage, P.Whh1b, gh1);
        if (wp == 0 && s < TT) {
            const ushort* zt = P.Z0 + ((size_t)s * BB + row0 + l15) * G3;
#pragma unroll
            for (int g = 0; g < 3; g++) {
                union { unsigned long long u; ushort s4[4]; } z;
                z.u = *(const unsigned long long*)(zt + g * HH + bcol);
#pragma unroll
                for (int i = 0; i < 4; i++) gi0z[g][i] = bf2f(z.s4[i]);
            }
        }
        wait_();
        // POST: stage h0(s-1) [fresh]; wp0: gh0 + L0 epi ; wp1: gi1 + L1 epi
        stage(P.h0buf + (s & 1) * HSZ, h0stage);
        __syncthreads();
        if (wp == 0 && s < TT) {
            floatx4 gh0[3] = {};
            gemm3_lds(h0stage, P.Whh0b, gh0);
            gru_epi(gi0z, gh0, P.bhh0, h0f, P.h0buf + (1 - (s & 1)) * HSZ, nullptr);
        }
        if (wp == 1 && s >= 1) {
            int t = s - 1;
            floatx4 gi1[3] = {};
            gemm3_lds(h0stage, P.Wih1b, gi1);
            float4 bi0 = *(const float4*)&P.bih1[0 * HH + bcol];
            float4 bi1 = *(const float4*)&P.bih1[1 * HH + bcol];
            float4 bi2 = *(const float4*)&P.bih1[2 * HH + bcol];
            const float* b0 = &bi0.x; const float* b1 = &bi1.x; const float* b2 = &bi2.x;
#pragma unroll
            for (int i = 0; i < 4; i++) { gi1[0][i] += b0[i]; gi1[1][i] += b1[i]; gi1[2][i] += b2[i]; }
            gru_epi(gi1, gh1, P.bhh1, h1f, P.h1buf + (s & 1) * HSZ, P.outs + (size_t)t * BB * HH);
        }
    }

    // ---- decoder: 2 phases per step ----
    for (int t = 0; t < TT; t++) {
        int pp = t & 1;
        // ---- phase A: pred(t-1) [wp1] + L0(t) [wp0] ----
        release();
        // PRE: stage h0(t-1) [stale]; wp0: gh0 + Zpe/Zvel
        stage(P.h0buf + pp * HSZ, h0stage);
        __syncthreads();
        floatx4 gh0[3] = {}, zadd[3];
        if (wp == 0) {
            gemm3_lds(h0stage, P.Whh0b, gh0);
            const float* zp = P.Zpe + (size_t)t * G3;
#pragma unroll
            for (int g = 0; g < 3; g++) {
                float4 z4 = *(const float4*)&zp[g * HH + bcol];
                const float* zp4 = &z4.x;
#pragma unroll
                for (int i = 0; i < 4; i++) zadd[g][i] = zp4[i];
            }
            if (t == 0) {
                const float* zv = P.Zvel + (size_t)(row0 + l15) * G3;
#pragma unroll
                for (int g = 0; g < 3; g++) {
                    float4 z4 = *(const float4*)&zv[g * HH + bcol];
                    const float* zp4 = &z4.x;
#pragma unroll
                    for (int i = 0; i < 4; i++) zadd[g][i] += zp4[i];
                }
            }
        }
        wait_();
        // POST: stage h1(t-1) [fresh]; wp1: pred(t-1); then wp0: gi0 + epi h0(t)
        stage(P.h1buf + pp * HSZ, h1stage);
        __syncthreads();
        if (t > 0) {
            if (wp == 1) pred_part(t - 1);
            __syncthreads();   // predb ready for wp0's gi0
        }
        if (wp == 0) {
            floatx4 gi0[3] = {};
            if (t > 0) {
                const ushort* a0 = P.Wih0b + (size_t)(0 * HH + ct + l15) * RNN_IN + q * 8;
                const ushort* a1 = P.Wih0b + (size_t)(1 * HH + ct + l15) * RNN_IN + q * 8;
                const ushort* a2 = P.Wih0b + (size_t)(2 * HH + ct + l15) * RNN_IN + q * 8;
                for (int kt = 0; kt < 3; kt++) {
                    bhalf8 b = *(const bhalf8*)(&predb[l15][kt * 32 + q * 8]);
                    gi0[0] = MFMA16(ld8(a0), b, gi0[0], 0, 0, 0); a0 += 32;
                    gi0[1] = MFMA16(ld8(a1), b, gi0[1], 0, 0, 0); a1 += 32;
                    gi0[2] = MFMA16(ld8(a2), b, gi0[2], 0, 0, 0); a2 += 32;
                }
            }
#pragma unroll
            for (int g = 0; g < 3; g++)
#pragma unroll
                for (int i = 0; i < 4; i++) gi0[g][i] += zadd[g][i];
            gru_epi(gi0, gh0, P.bhh0, h0f, P.h0buf + (1 - pp) * HSZ, nullptr);
        }

        // ---- phase B: L1(t) [wp1] ----
        release();
        // PRE: wp1: gh1 from resident h1stage
        floatx4 gh1[3] = {};
        if (wp == 1) gemm3_lds(h1stage, P.Whh1b, gh1);
        wait_();
        // POST: stage h0(t) [fresh]; wp1: gi1 + epi h1(t)
        stage(P.h0buf + (1 - pp) * HSZ, h0stage);
        __syncthreads();
        if (wp == 1) {
            floatx4 gi1[3] = {};
            gemm3_lds(h0stage, P.Wih1b, gi1);
            float4 bi0 = *(const float4*)&P.bih1[0 * HH + bcol];
            float4 bi1 = *(const float4*)&P.bih1[1 * HH + bcol];
            float4 bi2 = *(const float4*)&P.bih1[2 * HH + bcol];
            const float* b0 = &bi0.x; const float* b1 = &bi1.x; const float* b2 = &bi2.x;
#pragma unroll
            for (int i = 0; i < 4; i++) { gi1[0][i] += b0[i]; gi1[1][i] += b1[i]; gi1[2][i] += b2[i]; }
            gru_epi(gi1, gh1, P.bhh1, h1f, P.h1buf + (1 - pp) * HSZ, nullptr);
        }
    }
    // tail: pred(49); h1(49) in h1buf[0]
    release();
    wait_();
    stage(P.h1buf + 0 * HSZ, h1stage);
    __syncthreads();
    if (wp == 1) pred_part(TT - 1);
}

// ================= host =================
extern "C" void kernel_launch(void* const* d_in, const int* in_sizes, int n_in,
                              void* d_out, int out_size, void* d_ws, size_t ws_size,
                              hipStream_t stream)
{
    const float* input = (const float*)d_in[0];
    const float* W_ih0 = (const float*)d_in[1];
    const float* W_hh0 = (const float*)d_in[2];
    const float* b_ih0 = (const float*)d_in[3];
    const float* b_hh0 = (const float*)d_in[4];
    const float* W_ih1 = (const float*)d_in[5];
    const float* W_hh1 = (const float*)d_in[6];
    const float* b_ih1 = (const float*)d_in[7];
    const float* b_hh1 = (const float*)d_in[8];
    const float* W_lin = (const float*)d_in[9];
    const float* b_lin = (const float*)d_in[10];
    float* out = (float*)d_out;

    char* ws = (char*)d_ws;
    size_t off = 0;
    auto alloc = [&](size_t bytes) -> char* {
        off = (off + 255) & ~(size_t)255;
        char* p = ws + off;
        off += bytes;
        return p;
    };

    ushort* Wih0b = (ushort*)alloc((size_t)G3 * RNN_IN * 2);
    ushort* Whh0b = (ushort*)alloc((size_t)G3 * HH * 2);
    ushort* Wih1b = (ushort*)alloc((size_t)G3 * HH * 2);
    ushort* Whh1b = (ushort*)alloc((size_t)G3 * HH * 2);
    ushort* Wlinb = (ushort*)alloc((size_t)FF * HH * 2);
    ushort* x_en  = (ushort*)alloc((size_t)TT * BB * RNN_IN * 2);
    ushort* Z0    = (ushort*)alloc((size_t)TT * BB * G3 * 2);
    ushort* outs  = (ushort*)alloc((size_t)TT * BB * HH * 2);
    float*  Zpe   = (float*)alloc((size_t)TT * G3 * 4);
    float*  Zvel  = (float*)alloc((size_t)BB * G3 * 4);
    float*  pe    = (float*)alloc((size_t)100 * FF * 4);
    float*  maskp = (float*)alloc((size_t)BB * FF * 4);
    ushort* hb    = (ushort*)alloc((size_t)4 * BB * HH * 2);   // h0buf[2] + h1buf[2]
    unsigned* bar = (unsigned*)alloc(16384 * 4);               // 256 slots x 256B
    (void)ws_size; (void)in_sizes; (void)n_in; (void)out_size;

    dim3 blk(256);

    prep_weights<<<dim3(512), blk, 0, stream>>>(W_ih0, W_hh0, W_ih1, W_hh1, W_lin,
                                                Wih0b, Whh0b, Wih1b, Whh1b, Wlinb);
    {
        int total = TT * BB * RNN_IN + BB * FF + 100 * FF + 4 * BB * HH + 16384;
        prep_misc<<<dim3((total + 255) / 256), blk, 0, stream>>>(
            input, pe, maskp, x_en, hb, bar);
    }
    gemm_z0<<<dim3(TT * BB / 64, G3 / 96), blk, 0, stream>>>(x_en, Wih0b, b_ih0, Z0);
    zpe_kernel<<<dim3((TT * G3 + 255) / 256), blk, 0, stream>>>(pe, W_ih0, b_ih0, Zpe);
    zvel_kernel<<<dim3((BB * G3 + 255) / 256), blk, 0, stream>>>(input, W_ih0, Zvel);

    PArgs P;
    P.Z0 = Z0; P.Wih0b = Wih0b; P.Whh0b = Whh0b; P.Wih1b = Wih1b; P.Whh1b = Whh1b; P.Wlinb = Wlinb;
    P.bhh0 = b_hh0; P.bih1 = b_ih1; P.bhh1 = b_hh1; P.blin = b_lin;
    P.Zpe = Zpe; P.Zvel = Zvel; P.maskp = maskp; P.input = input;
    P.h0buf = hb; P.h1buf = hb + 2 * HSZ;
    P.outs = outs; P.out = out; P.slots = bar;

    void* kargs[] = { &P };
    hipError_t e = hipLaunchCooperativeKernel((void*)persistent12, dim3(256), dim3(256), kargs, 0, stream);
    (void)e;

    gemm_out_enc<<<dim3(TT * BB / 64, 1), blk, 0, stream>>>(outs, Wlinb, b_lin, input, out);
}